// Round 8
// baseline (83.767 us; speedup 1.0000x reference)
//
#include <hip/hip_runtime.h>
#include <hip/hip_bf16.h>

typedef __attribute__((ext_vector_type(8))) short short8;
typedef __attribute__((ext_vector_type(4))) float f32x4;

#define NROW 8192
#define DIM 512
#define BHALF 4096
#define NB2 32           // number of 256-row blocks
#define BT 256           // tile size
#define NPAIR2 528       // NB2*(NB2+1)/2
#define XCHUNK2 66       // 528/8

__device__ __forceinline__ void gload_lds16(const void* g, void* l) {
  __builtin_amdgcn_global_load_lds(
      (const __attribute__((address_space(1))) void*)g,
      (__attribute__((address_space(3))) void*)l,
      16, 0, 0);
}

// ---------------- Kernel 1: row L2-normalize fp32 -> bf16 (wave per row) ----------------
__global__ __launch_bounds__(256) void normalize_kernel(const float* __restrict__ in,
                                                        __hip_bfloat16* __restrict__ out) {
  const int w = threadIdx.x >> 6, lane = threadIdx.x & 63;
  const int row = blockIdx.x * 4 + w;
  const float4* src = (const float4*)(in + (size_t)row * DIM) + lane * 2;
  const float4 v0 = src[0], v1 = src[1];
  float ss = v0.x * v0.x + v0.y * v0.y + v0.z * v0.z + v0.w * v0.w
           + v1.x * v1.x + v1.y * v1.y + v1.z * v1.z + v1.w * v1.w;
  #pragma unroll
  for (int m = 1; m < 64; m <<= 1) ss += __shfl_xor(ss, m);
  const float inv = 1.0f / fmaxf(sqrtf(ss), 1e-12f);
  __hip_bfloat16 o[8];
  o[0] = __float2bfloat16(v0.x * inv); o[1] = __float2bfloat16(v0.y * inv);
  o[2] = __float2bfloat16(v0.z * inv); o[3] = __float2bfloat16(v0.w * inv);
  o[4] = __float2bfloat16(v1.x * inv); o[5] = __float2bfloat16(v1.y * inv);
  o[6] = __float2bfloat16(v1.z * inv); o[7] = __float2bfloat16(v1.w * inv);
  *(short8*)(out + (size_t)row * DIM + lane * 8) = *(const short8*)o;
}

// ---------------- Kernel 2: symmetric 256x256 pair-tile Gram + exp-sums ----------------
// 528 blocks (ib<=jb pairs of 256-row blocks), 512 threads = 8 waves (2M x 4N),
// per-wave output 128x64 (8x4 frags). BK=64, 128 KB dbuf LDS, XOR-swizzled
// (proven 0-conflict). K-tile split into 4 quadrant-phases, ONE raw s_barrier
// each: {stage half(s) -> counted vmcnt -> barrier -> ds_read -> MFMA(setprio)}.
// Single per-tile wait vmcnt(4) at ph0 (issued after next-tile A-stages) ->
// never drains to 0 in steady state; all halves have >=2 phases latency cover.
// Operand-holding: quadrant path (0,0)->(0,1)->(1,1)->(1,0) reuses a0,b1,a1.
__global__ __launch_bounds__(512, 2) void pair_gram_kernel(const __hip_bfloat16* __restrict__ f,
                                                           float* __restrict__ psum,
                                                           float* __restrict__ ppos) {
  __shared__ __align__(16) char lds[131072];  // [buf:64K][ A0|A1 | B0|B1 ] halves of 16K

  // --- XCD swizzle + 8x8 macro-tiled triangular pair decode (scalar-uniform) ---
  const int bid = blockIdx.x;
  const int wg = (bid & 7) * XCHUNK2 + (bid >> 3);
  int rem = wg, MI = 0, MJ = 0;
  {
    bool brk = false;
    for (MI = 0; MI < 4 && !brk; ++MI) {
      for (MJ = MI; MJ < 4; ++MJ) {
        const int sz = (MI == MJ) ? 36 : 64;
        if (rem < sz) { brk = true; break; }
        rem -= sz;
      }
    }
    if (brk) --MI;
  }
  int ib, jb;
  if (MI == MJ) {
    int i = 0, b = 0;
    while (b + (8 - i) <= rem) { b += 8 - i; ++i; }
    ib = MI * 8 + i; jb = MI * 8 + i + (rem - b);
  } else {
    ib = MI * 8 + (rem >> 3); jb = MJ * 8 + (rem & 7);
  }

  const int tid = threadIdx.x;
  const int lane = tid & 63;
  const int w = tid >> 6;            // wave 0..7
  const int wm = w >> 2;             // row half (0/1): rows wm*128..+128
  const int wn = w & 3;              // col quarter: cols wn*64..+64
  const int fr = lane & 15;
  const int g = lane >> 4;
  const int f7 = fr & 7;

  // staging source (inverse-swizzled): lane covers row w*8+(lane>>3) (+64 for
  // 2nd load), global col16 (lane&7)^((lane>>3)&7); LDS dest linear.
  const int srow8 = lane >> 3;
  const int scol = (lane & 7) ^ srow8;
  const __hip_bfloat16* gA = f + (size_t)(ib * BT + w * 8 + srow8) * DIM + scol * 8;
  const __hip_bfloat16* gB = f + (size_t)(jb * BT + w * 8 + srow8) * DIM + scol * 8;
  char* const L = (char*)lds;

  // fragment-read offsets (swizzled): row r at byte r*128, k-slot (kk*4+g)^ (r&7)
  const int sk0 = ((0 + g) ^ f7) * 16;
  const int sk1 = ((4 + g) ^ f7) * 16;
  const int aoff = (wm * 128 + fr) * 128;           // + qr*8192 + mi*2048
  const int boff = 32768 + (wn * 64 + fr) * 128;    // + qc*4096 + ni*2048

  f32x4 acc[8][4];
  const f32x4 zero = {0.f, 0.f, 0.f, 0.f};
  #pragma unroll
  for (int mi = 0; mi < 8; ++mi)
    #pragma unroll
    for (int ni = 0; ni < 4; ++ni) acc[mi][ni] = zero;

  #define STAGEH(ldsHalf, gptr, koff)                                  \
    { char* _d = (ldsHalf) + w * 1024;                                 \
      const __hip_bfloat16* _s = (gptr) + (koff);                      \
      gload_lds16(_s, _d);                                             \
      gload_lds16(_s + (size_t)64 * DIM, _d + 8192); }

  #define LDA(dst, base, qr)                                                        \
    _Pragma("unroll") for (int kk = 0; kk < 2; ++kk)                                \
    _Pragma("unroll") for (int mi = 0; mi < 4; ++mi)                                \
      dst[kk][mi] = *(const short8*)((base) + aoff + (qr) * 8192 + mi * 2048 + (kk ? sk1 : sk0));

  #define LDB(dst, base, qc)                                                        \
    _Pragma("unroll") for (int kk = 0; kk < 2; ++kk)                                \
    _Pragma("unroll") for (int ni = 0; ni < 2; ++ni)                                \
      dst[kk][ni] = *(const short8*)((base) + boff + (qc) * 4096 + ni * 2048 + (kk ? sk1 : sk0));

  #define MF(qr, qc, a, b)                                                          \
    __builtin_amdgcn_s_setprio(1);                                                  \
    _Pragma("unroll") for (int kk = 0; kk < 2; ++kk)                                \
    _Pragma("unroll") for (int mi = 0; mi < 4; ++mi)                                \
    _Pragma("unroll") for (int ni = 0; ni < 2; ++ni)                                \
      acc[(qr) * 4 + mi][(qc) * 2 + ni] = __builtin_amdgcn_mfma_f32_16x16x32_bf16(  \
          a[kk][mi], b[kk][ni], acc[(qr) * 4 + mi][(qc) * 2 + ni], 0, 0, 0);        \
    __builtin_amdgcn_s_setprio(0);

  // prologue: stage tile 0 (A0,A1,B0,B1) into buf0; the loop's ph0 wait covers it
  STAGEH(L + 0,     gA, 0);
  STAGEH(L + 16384, gA + (size_t)128 * DIM, 0);
  STAGEH(L + 32768, gB, 0);
  STAGEH(L + 49152, gB + (size_t)128 * DIM, 0);

  #pragma unroll 2
  for (int t = 0; t < 8; ++t) {
    char* const Ab = L + (t & 1) * 65536;
    char* const S  = L + ((t & 1) ^ 1) * 65536;
    const int kn = (t + 1) * 64;
    short8 a0[2][4], a1[2][4], b0[2][2], b1[2][2], b0r[2][2];

    // ---- phase 0: Q(0,0); stage A0,A1(t+1); the one counted wait per tile ----
    if (t < 7) {
      STAGEH(S + 0,     gA, kn);
      STAGEH(S + 16384, gA + (size_t)128 * DIM, kn);
      asm volatile("s_waitcnt vmcnt(4)" ::: "memory");  // tile t's 4 halves landed
    } else {
      asm volatile("s_waitcnt vmcnt(0)" ::: "memory");  // tail drain (2-phase cover)
    }
    __builtin_amdgcn_s_barrier();
    LDA(a0, Ab, 0);
    LDB(b0, Ab, 0);
    MF(0, 0, a0, b0);

    // ---- phase 1: Q(0,1); stage B0(t+1); a0 held ----
    if (t < 7) STAGEH(S + 32768, gB, kn);
    __builtin_amdgcn_s_barrier();
    LDB(b1, Ab, 1);
    MF(0, 1, a0, b1);

    // ---- phase 2: Q(1,1); stage B1(t+1); b1 held ----
    if (t < 7) STAGEH(S + 49152, gB + (size_t)128 * DIM, kn);
    __builtin_amdgcn_s_barrier();
    LDA(a1, Ab, 1);
    MF(1, 1, a1, b1);

    // ---- phase 3: Q(1,0); a1 held ----
    __builtin_amdgcn_s_barrier();
    LDB(b0r, Ab, 0);
    MF(1, 0, a1, b0r);
  }
  #undef STAGEH
  #undef LDA
  #undef LDB
  #undef MF

  // ---- epilogue: exp, row-sums (rows of ib) + col-sums (rows of jb), pos-pair ----
  __syncthreads();
  float* sc = (float*)L;   // rS[wn][256]@0, rP@1024, cS[wm][256]@2048, cP@2560
  float csum[4] = {0.f, 0.f, 0.f, 0.f}, pcol[4] = {0.f, 0.f, 0.f, 0.f};

  #pragma unroll
  for (int mi = 0; mi < 8; ++mi) {
    float rs4[4] = {0.f, 0.f, 0.f, 0.f}, pp4[4] = {0.f, 0.f, 0.f, 0.f};
    #pragma unroll
    for (int ni = 0; ni < 4; ++ni) {
      const int gcol = jb * BT + wn * 64 + ni * 16 + fr;
      #pragma unroll
      for (int r = 0; r < 4; ++r) {
        const int grow = ib * BT + wm * 128 + mi * 16 + g * 4 + r;
        const float dot = acc[mi][ni][r];
        const float e = (gcol == grow) ? 0.f : __expf((dot - 1.0f) * 10.0f);
        const float pos = (gcol == (grow ^ BHALF)) ? dot : 0.f;
        rs4[r] += e;  pp4[r] += pos;
        csum[ni] += e;  pcol[ni] += pos;
      }
    }
    #pragma unroll
    for (int r = 0; r < 4; ++r) {
      float a = rs4[r], b = pp4[r];
      #pragma unroll
      for (int msk = 1; msk < 16; msk <<= 1) { a += __shfl_xor(a, msk); b += __shfl_xor(b, msk); }
      rs4[r] = a; pp4[r] = b;
    }
    if (fr == 0) {
      #pragma unroll
      for (int r = 0; r < 4; ++r) {
        const int row = wm * 128 + mi * 16 + g * 4 + r;
        sc[wn * 256 + row]        = rs4[r];
        sc[1024 + wn * 256 + row] = pp4[r];
      }
    }
  }
  #pragma unroll
  for (int ni = 0; ni < 4; ++ni) {
    float a = csum[ni], b = pcol[ni];
    a += __shfl_xor(a, 16); b += __shfl_xor(b, 16);
    a += __shfl_xor(a, 32); b += __shfl_xor(b, 32);
    if (g == 0) {
      const int col = wn * 64 + ni * 16 + fr;
      sc[2048 + wm * 256 + col] = a;
      sc[2560 + wm * 256 + col] = b;
    }
  }
  __syncthreads();

  if (tid < 256) {                     // rows of block ib -> slot jb
    const int row = tid;
    const float s = sc[row] + sc[256 + row] + sc[512 + row] + sc[768 + row];
    const float p = sc[1024 + row] + sc[1280 + row] + sc[1536 + row] + sc[1792 + row];
    psum[(size_t)jb * NROW + ib * BT + row] = s;
    ppos[(size_t)jb * NROW + ib * BT + row] = p;
  } else if (ib != jb) {               // rows of block jb -> slot ib (transpose side)
    const int col = tid - 256;
    const float s = sc[2048 + col] + sc[2304 + col];
    const float p = sc[2560 + col] + sc[2816 + col];
    psum[(size_t)ib * NROW + jb * BT + col] = s;
    ppos[(size_t)ib * NROW + jb * BT + col] = p;
  }
}

// ---------------- Kernel 3a: per-row loss, 64 partials ----------------
__global__ __launch_bounds__(128) void loss_stage1(const float* __restrict__ psum,
                                                   const float* __restrict__ ppos,
                                                   float* __restrict__ partial) {
  const int row = blockIdx.x * 128 + threadIdx.x;
  float s = 0.f, p = 0.f;
  #pragma unroll 8
  for (int sl = 0; sl < NB2; ++sl) {
    s += psum[(size_t)sl * NROW + row];
    p += ppos[(size_t)sl * NROW + row];
  }
  float local = logf(s) + 10.0f - 10.0f * p;
  #pragma unroll
  for (int m = 1; m < 64; m <<= 1) local += __shfl_xor(local, m);
  __shared__ float red[2];
  if ((threadIdx.x & 63) == 0) red[threadIdx.x >> 6] = local;
  __syncthreads();
  if (threadIdx.x == 0) partial[blockIdx.x] = red[0] + red[1];
}

// ---------------- Kernel 3b: final scalar ----------------
__global__ __launch_bounds__(64) void loss_stage2(const float* __restrict__ partial,
                                                  float* __restrict__ out) {
  float v = partial[threadIdx.x];
  #pragma unroll
  for (int m = 1; m < 64; m <<= 1) v += __shfl_xor(v, m);
  if (threadIdx.x == 0) out[0] = v * (1.0f / (float)BHALF);
}

extern "C" void kernel_launch(void* const* d_in, const int* in_sizes, int n_in,
                              void* d_out, int out_size, void* d_ws, size_t ws_size,
                              hipStream_t stream) {
  const float* feat = (const float*)d_in[0];
  char* ws = (char*)d_ws;
  __hip_bfloat16* f = (__hip_bfloat16*)ws;                         // 8 MB
  float* psum = (float*)(ws + (size_t)NROW * DIM * 2);             // NB2*NROW floats (1 MB)
  float* ppos = psum + (size_t)NB2 * NROW;                         // 1 MB
  float* partial = ppos + (size_t)NB2 * NROW;                      // 64 floats
  float* out = (float*)d_out;

  normalize_kernel<<<NROW / 4, 256, 0, stream>>>(feat, f);
  pair_gram_kernel<<<NPAIR2, 512, 0, stream>>>(f, psum, ppos);
  loss_stage1<<<NROW / 128, 128, 0, stream>>>(psum, ppos, partial);
  loss_stage2<<<1, 64, 0, stream>>>(partial, out);
}